// Round 1
// baseline (182.267 us; speedup 1.0000x reference)
//
#include <hip/hip_runtime.h>
#include <hip/hip_bf16.h>

// SparseDropout:
//   out0 = indices (passthrough, written as float32 since the tuple output
//          buffer is read back as one flat float32 array)
//   out1 = mask ? values * (1/KPROB) : 0   with KPROB = 0.5 -> scale = 2.0f
//
// Pure memory-bound elementwise. Vectorized 4-wide, capped grid-stride.

__global__ __launch_bounds__(256) void sd_idx_copy(const int* __restrict__ idx,
                                                   float* __restrict__ out,
                                                   long long n4) {
    long long i = (long long)blockIdx.x * blockDim.x + threadIdx.x;
    long long stride = (long long)gridDim.x * blockDim.x;
    const int4* __restrict__ src = (const int4*)idx;
    float4* __restrict__ dst = (float4*)out;
    for (; i < n4; i += stride) {
        int4 v = src[i];
        float4 o;
        o.x = (float)v.x;
        o.y = (float)v.y;
        o.z = (float)v.z;
        o.w = (float)v.w;
        dst[i] = o;
    }
}

__global__ __launch_bounds__(256) void sd_dropout(const float* __restrict__ vals,
                                                  const int* __restrict__ mask,
                                                  float* __restrict__ out,
                                                  long long n4) {
    long long i = (long long)blockIdx.x * blockDim.x + threadIdx.x;
    long long stride = (long long)gridDim.x * blockDim.x;
    const float4* __restrict__ vsrc = (const float4*)vals;
    const int4* __restrict__ msrc = (const int4*)mask;
    float4* __restrict__ dst = (float4*)out;
    const float scale = 2.0f;  // 1 / KPROB, KPROB = 0.5
    for (; i < n4; i += stride) {
        float4 v = vsrc[i];
        int4 m = msrc[i];
        float4 o;
        o.x = m.x ? v.x * scale : 0.0f;
        o.y = m.y ? v.y * scale : 0.0f;
        o.z = m.z ? v.z * scale : 0.0f;
        o.w = m.w ? v.w * scale : 0.0f;
        dst[i] = o;
    }
}

extern "C" void kernel_launch(void* const* d_in, const int* in_sizes, int n_in,
                              void* d_out, int out_size, void* d_ws, size_t ws_size,
                              hipStream_t stream) {
    const int* indices = (const int*)d_in[0];    // (2, NNZ) flattened: in_sizes[0] = 2*NNZ
    const float* values = (const float*)d_in[1]; // (NNZ,)
    const int* mask = (const int*)d_in[2];       // (NNZ,) bool -> int32 per harness contract

    const long long n_idx = in_sizes[0];  // 64,000,000
    const long long n_val = in_sizes[1];  // 32,000,000

    float* out_idx = (float*)d_out;
    float* out_val = (float*)d_out + n_idx;

    const int block = 256;
    const long long n_idx4 = n_idx / 4;  // divisible: 64M % 4 == 0
    const long long n_val4 = n_val / 4;  // divisible: 32M % 4 == 0

    int grid_idx = (int)((n_idx4 + block - 1) / block);
    if (grid_idx > 2048) grid_idx = 2048;
    int grid_val = (int)((n_val4 + block - 1) / block);
    if (grid_val > 2048) grid_val = 2048;

    sd_idx_copy<<<grid_idx, block, 0, stream>>>(indices, out_idx, n_idx4);
    sd_dropout<<<grid_val, block, 0, stream>>>(values, mask, out_val, n_val4);
}

// Round 3
// 162.031 us; speedup vs baseline: 1.1249x; 1.1249x over previous
//
#include <hip/hip_runtime.h>
#include <hip/hip_bf16.h>

// SparseDropout, fused single-launch version:
//   units [0, n_idx4):          out0[i]  = (float)indices[i]   (int4 -> float4)
//   units [n_idx4, n_tot4):     out1[j]  = mask[j] ? values[j]*2 : 0
// All traffic is streaming with zero reuse -> nontemporal loads/stores to
// avoid L2/L3 pollution. One launch removes the inter-kernel gap + drain tail.
// Native clang ext_vector types (not HIP_vector_type) — required by
// __builtin_nontemporal_load/store.

typedef int   i32x4 __attribute__((ext_vector_type(4)));
typedef float f32x4 __attribute__((ext_vector_type(4)));

__global__ __launch_bounds__(256) void sd_fused(const int* __restrict__ idx,
                                                const float* __restrict__ vals,
                                                const int* __restrict__ mask,
                                                float* __restrict__ out_idx,
                                                float* __restrict__ out_val,
                                                long long n_idx4,
                                                long long n_tot4) {
    long long i = (long long)blockIdx.x * blockDim.x + threadIdx.x;
    const long long stride = (long long)gridDim.x * blockDim.x;
    const float scale = 2.0f;  // 1 / KPROB, KPROB = 0.5

    for (; i < n_tot4; i += stride) {
        if (i < n_idx4) {
            i32x4 v = __builtin_nontemporal_load((const i32x4*)idx + i);
            f32x4 o;
            o.x = (float)v.x;
            o.y = (float)v.y;
            o.z = (float)v.z;
            o.w = (float)v.w;
            __builtin_nontemporal_store(o, (f32x4*)out_idx + i);
        } else {
            long long j = i - n_idx4;
            f32x4 v = __builtin_nontemporal_load((const f32x4*)vals + j);
            i32x4 m = __builtin_nontemporal_load((const i32x4*)mask + j);
            f32x4 o;
            o.x = m.x ? v.x * scale : 0.0f;
            o.y = m.y ? v.y * scale : 0.0f;
            o.z = m.z ? v.z * scale : 0.0f;
            o.w = m.w ? v.w * scale : 0.0f;
            __builtin_nontemporal_store(o, (f32x4*)out_val + j);
        }
    }
}

extern "C" void kernel_launch(void* const* d_in, const int* in_sizes, int n_in,
                              void* d_out, int out_size, void* d_ws, size_t ws_size,
                              hipStream_t stream) {
    const int* indices = (const int*)d_in[0];    // (2, NNZ) flattened int32
    const float* values = (const float*)d_in[1]; // (NNZ,) f32
    const int* mask = (const int*)d_in[2];       // (NNZ,) bool -> int32

    const long long n_idx = in_sizes[0];  // 64,000,000
    const long long n_val = in_sizes[1];  // 32,000,000

    float* out_idx = (float*)d_out;
    float* out_val = (float*)d_out + n_idx;

    const long long n_idx4 = n_idx / 4;            // 16M
    const long long n_tot4 = n_idx4 + n_val / 4;   // 24M

    const int block = 256;
    int grid = (int)((n_tot4 + block - 1) / block);
    if (grid > 2048) grid = 2048;

    sd_fused<<<grid, block, 0, stream>>>(indices, values, mask,
                                         out_idx, out_val, n_idx4, n_tot4);
}